// Round 6
// baseline (158.936 us; speedup 1.0000x reference)
//
#include <hip/hip_runtime.h>
#include <hip/hip_bf16.h>
#include <cstdint>
#include <cstddef>

typedef __hip_bfloat16 bf16;
typedef __attribute__((ext_vector_type(8))) short bf16x8;
typedef __attribute__((ext_vector_type(4))) float f32x4;

#define AS1C(p) ((const __attribute__((address_space(1))) void*)(p))
#define AS3(p)  ((__attribute__((address_space(3))) void*)(p))

constexpr int B_ = 2, S_ = 2048, E_ = 1024, H_ = 16, D_ = 64;
constexpr int M_ = B_ * S_;                      // 4096
constexpr float QSCALE_ = 0.125f * 1.44269504088896340736f;  // 1/sqrt(64) * log2(e)

__device__ __forceinline__ void gload_lds16(const bf16* g, bf16* l) {
  __builtin_amdgcn_global_load_lds(AS1C(g), AS3(l), 16, 0, 0);
}

__device__ __forceinline__ void cast4(const float* __restrict__ in, bf16* __restrict__ out, int i) {
  float4 v = reinterpret_cast<const float4*>(in)[i];
  union { bf16 b[4]; short4 s; } u;
  u.b[0] = __float2bfloat16(v.x);
  u.b[1] = __float2bfloat16(v.y);
  u.b[2] = __float2bfloat16(v.z);
  u.b[3] = __float2bfloat16(v.w);
  reinterpret_cast<short4*>(out)[i] = u.s;
}

// ---------------- fused prep: casts + rope tables + bias concat ----------------
__global__ void prep_kernel(const float* __restrict__ x,
                            const float* __restrict__ Wq, const float* __restrict__ Wk,
                            const float* __restrict__ Wv, const float* __restrict__ Wo,
                            const float* __restrict__ bq, const float* __restrict__ bk,
                            const float* __restrict__ bv,
                            bf16* __restrict__ xb, bf16* __restrict__ Wqkvb,
                            bf16* __restrict__ Wob, float* __restrict__ bqkv,
                            float* __restrict__ sintab, float* __restrict__ costab) {
  const int b = blockIdx.x, t = threadIdx.x;
  if (b < 4096) {
    cast4(x, xb, b * 256 + t);
  } else if (b < 5120) {
    cast4(Wo, Wob, (b - 4096) * 256 + t);
  } else if (b < 8192) {
    const int i = (b - 5120) * 256 + t;
    const int which = i >> 18;
    const int j = i & ((1 << 18) - 1);
    const float* src = which == 0 ? Wq : (which == 1 ? Wk : Wv);
    cast4(src, Wqkvb + (size_t)which * E_ * E_, j);
  } else if (b < 8448) {
    const int idx = (b - 8192) * 256 + t;
    const int s = idx >> 5, i = idx & 31;
    float inv = powf(10000.0f, -(float)i / 32.0f);
    float ang = (float)s * inv;
    sintab[idx] = sinf(ang);
    costab[idx] = cosf(ang);
  } else {
    for (int j = t; j < 768; j += 256) {
      const int which = j >> 8, jj = j & 255;
      const float* src = which == 0 ? bq : (which == 1 ? bk : bv);
      reinterpret_cast<float4*>(bqkv)[j] = reinterpret_cast<const float4*>(src)[jj];
    }
  }
}

// ---------------- QKV GEMM: C = x * Wqkv^T + bias; rope q/k; V stored TRANSPOSED ----------------
// Q,K scatter to [b][h][s][d]; V scatters to [b][h][d][s] (so attention stages V^T directly).
__global__ __launch_bounds__(256)
void gemm_qkv(const bf16* __restrict__ A, const bf16* __restrict__ W,
              const float* __restrict__ bias,
              bf16* __restrict__ Qo, bf16* __restrict__ Ko, bf16* __restrict__ Vo,
              const float* __restrict__ sintab, const float* __restrict__ costab)
{
  constexpr int K = 1024, BK = 32;
  __shared__ __align__(16) bf16 As[128 * BK];
  __shared__ __align__(16) bf16 Bs[128 * BK];
  const int tid = threadIdx.x;
  const int lane = tid & 63, wid = tid >> 6;
  const int g = lane >> 4, r16 = lane & 15;
  const int wr = wid >> 1, wc = wid & 1;

  const int nwg = gridDim.x * gridDim.y;
  const int flat = blockIdx.y * gridDim.x + blockIdx.x;
  const int cpx = nwg >> 3;
  const int f2 = (flat & 7) * cpx + (flat >> 3);
  const int m0 = (f2 / gridDim.x) * 128, n0 = (f2 % gridDim.x) * 128;

  const f32x4 fz = {0.f, 0.f, 0.f, 0.f};
  f32x4 acc[4][4];
#pragma unroll
  for (int mi = 0; mi < 4; ++mi)
#pragma unroll
    for (int ni = 0; ni < 4; ++ni) acc[mi][ni] = fz;

  const bf16* Abase = A + (size_t)m0 * K;
  const bf16* Wbase = W + (size_t)n0 * K;
  const int c0 = tid, c1 = 256 + tid;

  for (int k0 = 0; k0 < K; k0 += BK) {
    __syncthreads();
    gload_lds16(Abase + (size_t)(c0 >> 2) * K + k0 + (c0 & 3) * 8, As + c0 * 8);
    gload_lds16(Abase + (size_t)(c1 >> 2) * K + k0 + (c1 & 3) * 8, As + c1 * 8);
    gload_lds16(Wbase + (size_t)(c0 >> 2) * K + k0 + (c0 & 3) * 8, Bs + c0 * 8);
    gload_lds16(Wbase + (size_t)(c1 >> 2) * K + k0 + (c1 & 3) * 8, Bs + c1 * 8);
    __syncthreads();

    bf16x8 af[4], bfr[4];
#pragma unroll
    for (int mi = 0; mi < 4; ++mi)
      af[mi] = *reinterpret_cast<const bf16x8*>(As + (wr * 64 + mi * 16 + r16) * BK + 8 * g);
#pragma unroll
    for (int ni = 0; ni < 4; ++ni)
      bfr[ni] = *reinterpret_cast<const bf16x8*>(Bs + (wc * 64 + ni * 16 + r16) * BK + 8 * g);
    __builtin_amdgcn_s_setprio(1);
#pragma unroll
    for (int mi = 0; mi < 4; ++mi)
#pragma unroll
      for (int ni = 0; ni < 4; ++ni)
        acc[mi][ni] = __builtin_amdgcn_mfma_f32_16x16x32_bf16(af[mi], bfr[ni], acc[mi][ni], 0, 0, 0);
    __builtin_amdgcn_s_setprio(0);
  }

#pragma unroll
  for (int mi = 0; mi < 4; ++mi) {
#pragma unroll
    for (int ni = 0; ni < 4; ++ni) {
      const int gn = n0 + wc * 64 + ni * 16 + r16;
      const float bv = bias[gn];
#pragma unroll
      for (int r = 0; r < 4; ++r) {
        const int gm = m0 + wr * 64 + mi * 16 + g * 4 + r;
        float val = acc[mi][ni][r] + bv;
        const int which = gn >> 10;
        const int d = gn & 63;
        const int srow = gm & (S_ - 1);
        if (which < 2) {
          const float cs = costab[srow * 32 + (d >> 1)];
          const float sn = sintab[srow * 32 + (d >> 1)];
          const float pv = __shfl_xor(val, 1);
          val = (d & 1) ? (val * cs + pv * sn) : (val * cs - pv * sn);
        }
        const int b = gm >> 11;
        const int h = (gn >> 6) & 15;
        const size_t bh = (size_t)(b * H_ + h);
        if (which == 0) {
          Qo[(bh * S_ + srow) * D_ + d] = __float2bfloat16(val * QSCALE_);
        } else if (which == 1) {
          Ko[(bh * S_ + srow) * D_ + d] = __float2bfloat16(val);
        } else {
          Vo[(bh * D_ + d) * S_ + srow] = __float2bfloat16(val);   // V^T
        }
      }
    }
  }
}

// ---------------- O-projection GEMM: BM=64 x BN=128 (512 blocks) ----------------
__global__ __launch_bounds__(256)
void gemm_o(const bf16* __restrict__ A, const bf16* __restrict__ W,
            const float* __restrict__ bias, float* __restrict__ outF)
{
  constexpr int K = 1024, BK = 32;
  __shared__ __align__(16) bf16 As[64 * BK];
  __shared__ __align__(16) bf16 Bs[128 * BK];
  const int tid = threadIdx.x;
  const int lane = tid & 63;
  const int wc = tid >> 6;                        // wave = n-quadrant of 32
  const int g = lane >> 4, r16 = lane & 15;

  const int flat = blockIdx.x;                    // 512
  const int f2 = (flat & 7) * 64 + (flat >> 3);   // bijective XCD swizzle
  const int m0 = (f2 >> 3) * 64, n0 = (f2 & 7) * 128;

  const f32x4 fz = {0.f, 0.f, 0.f, 0.f};
  f32x4 acc[4][2];
#pragma unroll
  for (int mi = 0; mi < 4; ++mi)
#pragma unroll
    for (int ni = 0; ni < 2; ++ni) acc[mi][ni] = fz;

  const bf16* Abase = A + (size_t)m0 * K;
  const bf16* Wbase = W + (size_t)n0 * K;
  const int c0 = tid, c1 = 256 + tid;

  for (int k0 = 0; k0 < K; k0 += BK) {
    __syncthreads();
    gload_lds16(Abase + (size_t)(c0 >> 2) * K + k0 + (c0 & 3) * 8, As + c0 * 8);
    gload_lds16(Wbase + (size_t)(c0 >> 2) * K + k0 + (c0 & 3) * 8, Bs + c0 * 8);
    gload_lds16(Wbase + (size_t)(c1 >> 2) * K + k0 + (c1 & 3) * 8, Bs + c1 * 8);
    __syncthreads();

    bf16x8 af[4], bfr[2];
#pragma unroll
    for (int mi = 0; mi < 4; ++mi)
      af[mi] = *reinterpret_cast<const bf16x8*>(As + (mi * 16 + r16) * BK + 8 * g);
#pragma unroll
    for (int ni = 0; ni < 2; ++ni)
      bfr[ni] = *reinterpret_cast<const bf16x8*>(Bs + (wc * 32 + ni * 16 + r16) * BK + 8 * g);
    __builtin_amdgcn_s_setprio(1);
#pragma unroll
    for (int mi = 0; mi < 4; ++mi)
#pragma unroll
      for (int ni = 0; ni < 2; ++ni)
        acc[mi][ni] = __builtin_amdgcn_mfma_f32_16x16x32_bf16(af[mi], bfr[ni], acc[mi][ni], 0, 0, 0);
    __builtin_amdgcn_s_setprio(0);
  }

#pragma unroll
  for (int mi = 0; mi < 4; ++mi)
#pragma unroll
    for (int ni = 0; ni < 2; ++ni) {
      const int gn = n0 + wc * 32 + ni * 16 + r16;
      const float bv = bias[gn];
#pragma unroll
      for (int r = 0; r < 4; ++r) {
        const int gm = m0 + mi * 16 + g * 4 + r;
        outF[(size_t)gm * 1024 + gn] = acc[mi][ni][r] + bv;
      }
    }
}

// ---------------- causal flash attention v6 ----------------
// Swapped QK^T (lane owns q = qw0+r16, 16 k's), in-register P repack via cvt_pk + bpermute,
// V^T staged from global [bh][d][s] via gload_lds. 1024 blocks heavy-first, 4 blocks/CU.
__global__ __launch_bounds__(256, 4)
void attn_kernel(const bf16* __restrict__ Q, const bf16* __restrict__ Kg,
                 const bf16* __restrict__ Vtg, bf16* __restrict__ Og)
{
  __shared__ __align__(16) bf16 Ks[2][64 * 64];   // [k][d], chunk-xor-swizzled source
  __shared__ __align__(16) bf16 Vs[2][64 * 64];   // [d][k], chunk-xor-swizzled source
  const int flat = blockIdx.x;
  const int bh = flat & 31;
  const int qblk = 31 - (flat >> 5);              // heavy-first
  const int tid = threadIdx.x, lane = tid & 63, wid = tid >> 6;
  const int g = lane >> 4, r16 = lane & 15;
  const bf16* Qb = Q + (size_t)bh * S_ * D_;
  const bf16* Kb = Kg + (size_t)bh * S_ * D_;
  const bf16* Vb = Vtg + (size_t)bh * D_ * S_;
  const int b = bh >> 4, h = bh & 15;
  bf16* Ob = Og + (size_t)b * S_ * E_ + h * D_;

  const int q0 = qblk * 64;
  const int qw0 = q0 + wid * 16;
  const int nkt = qblk + 1;
  const f32x4 fz = {0.f, 0.f, 0.f, 0.f};

  bf16x8 qf[2];
#pragma unroll
  for (int hh = 0; hh < 2; ++hh)
    qf[hh] = *reinterpret_cast<const bf16x8*>(Qb + (size_t)(qw0 + r16) * 64 + hh * 32 + 8 * g);

  f32x4 oacc[4];
#pragma unroll
  for (int dt = 0; dt < 4; ++dt) oacc[dt] = fz;
  float mrow = -__builtin_inff();
  float lrow = 0.f;

  const int kc0 = tid, kc1 = 256 + tid;
  const int glsrc = (g << 4) + (g << 2);          // 20*g: lane with r16' = 4g+r (group g)

  // stage helpers (pattern identical for K and V^T: 64 rows x 8 16B-chunks)
  auto stage = [&](const bf16* srcbase, size_t rowstride, bf16* dst) {
    const int r0 = kc0 >> 3, cc0 = kc0 & 7;
    gload_lds16(srcbase + (size_t)r0 * rowstride + ((cc0 ^ (r0 & 7)) * 8), dst + kc0 * 8);
    const int r1 = kc1 >> 3, cc1 = kc1 & 7;
    gload_lds16(srcbase + (size_t)r1 * rowstride + ((cc1 ^ (r1 & 7)) * 8), dst + kc1 * 8);
  };

  stage(Kb, 64, Ks[0]);
  stage(Vb, S_, Vs[0]);
  __syncthreads();
  int cur = 0;

  for (int kt = 0; kt < nkt; ++kt) {
    const int k0 = kt * 64;
    if (kt + 1 < nkt) {
      stage(Kb + (size_t)(k0 + 64) * 64, 64, Ks[cur ^ 1]);
      stage(Vb + (k0 + 64), S_, Vs[cur ^ 1]);
    }

    if (k0 <= qw0 + 15) {
      const bf16* ksp = Ks[cur];
      const bf16* vsp = Vs[cur];
      const int sw = r16 & 7;
      // ---- QK^T (swapped: A=K rows, B=Q rows) -> ps[kf][r] = S[q=qw0+r16][k=k0+kf*16+4g+r]
      f32x4 ps[4];
      __builtin_amdgcn_s_setprio(1);
#pragma unroll
      for (int kf = 0; kf < 4; ++kf) {
        const int krow = kf * 16 + r16;
        const bf16x8 ka = *reinterpret_cast<const bf16x8*>(&ksp[krow * 64 + ((g ^ sw) * 8)]);
        const bf16x8 kb = *reinterpret_cast<const bf16x8*>(&ksp[krow * 64 + (((g + 4) ^ sw) * 8)]);
        f32x4 sa = __builtin_amdgcn_mfma_f32_16x16x32_bf16(ka, qf[0], fz, 0, 0, 0);
        ps[kf] = __builtin_amdgcn_mfma_f32_16x16x32_bf16(kb, qf[1], sa, 0, 0, 0);
      }
      __builtin_amdgcn_s_setprio(0);
      // ---- causal mask ----
      if (k0 + 63 > qw0) {
        const int qmk = qw0 + r16 - k0;
#pragma unroll
        for (int kf = 0; kf < 4; ++kf)
#pragma unroll
          for (int r = 0; r < 4; ++r)
            if (kf * 16 + 4 * g + r > qmk) ps[kf][r] = -1e30f;
      }
      // ---- defer-max online softmax (lane-local row q = qw0+r16) ----
      float tm = fmaxf(fmaxf(ps[0][0], ps[0][1]), fmaxf(ps[0][2], ps[0][3]));
#pragma unroll
      for (int kf = 1; kf < 4; ++kf)
        tm = fmaxf(tm, fmaxf(fmaxf(ps[kf][0], ps[kf][1]), fmaxf(ps[kf][2], ps[kf][3])));
      tm = fmaxf(tm, __shfl_xor(tm, 16));
      tm = fmaxf(tm, __shfl_xor(tm, 32));
      if (__any((tm - mrow > 8.f) ? 1 : 0)) {
        const float mn = fmaxf(mrow, tm);
        const float scl = exp2f(mrow - mn);
        mrow = mn;
        lrow *= scl;
        float sclo[4];
#pragma unroll
        for (int r = 0; r < 4; ++r) sclo[r] = __shfl(scl, glsrc + r);
#pragma unroll
        for (int dt = 0; dt < 4; ++dt)
#pragma unroll
          for (int r = 0; r < 4; ++r) oacc[dt][r] *= sclo[r];
      }
      float ssum = 0.f;
#pragma unroll
      for (int kf = 0; kf < 4; ++kf)
#pragma unroll
        for (int r = 0; r < 4; ++r) {
          const float p = exp2f(ps[kf][r] - mrow);
          ps[kf][r] = p;
          ssum += p;
        }
      lrow += ssum;
      // ---- pack P to bf16 pairs in-register ----
      unsigned int pk[4][2];
#pragma unroll
      for (int kf = 0; kf < 4; ++kf)
#pragma unroll
        for (int w = 0; w < 2; ++w) {
          unsigned int rr;
          asm("v_cvt_pk_bf16_f32 %0, %1, %2" : "=v"(rr) : "v"(ps[kf][2 * w]), "v"(ps[kf][2 * w + 1]));
          pk[kf][w] = rr;
        }
      // ---- redistribute into PV A-fragments + PV MFMA ----
      const int srcA = ((g & 1) << 5) + r16;
      const bool ghi = g >= 2;
#pragma unroll
      for (int ks = 0; ks < 2; ++ks) {
        const unsigned int a0 = (unsigned)__shfl((int)pk[2 * ks][0], srcA);
        const unsigned int b0 = (unsigned)__shfl((int)pk[2 * ks + 1][0], srcA);
        const unsigned int a1 = (unsigned)__shfl((int)pk[2 * ks][1], srcA);
        const unsigned int b1 = (unsigned)__shfl((int)pk[2 * ks + 1][1], srcA);
        const unsigned int a2 = (unsigned)__shfl((int)pk[2 * ks][0], srcA + 16);
        const unsigned int b2 = (unsigned)__shfl((int)pk[2 * ks + 1][0], srcA + 16);
        const unsigned int a3 = (unsigned)__shfl((int)pk[2 * ks][1], srcA + 16);
        const unsigned int b3 = (unsigned)__shfl((int)pk[2 * ks + 1][1], srcA + 16);
        union { unsigned int w[4]; bf16x8 v; } aw;
        aw.w[0] = ghi ? b0 : a0;
        aw.w[1] = ghi ? b1 : a1;
        aw.w[2] = ghi ? b2 : a2;
        aw.w[3] = ghi ? b3 : a3;
        __builtin_amdgcn_s_setprio(1);
#pragma unroll
        for (int dt = 0; dt < 4; ++dt) {
          const int d = dt * 16 + r16;
          const bf16x8 vf = *reinterpret_cast<const bf16x8*>(
              &vsp[d * 64 + (((ks * 4 + g) ^ (r16 & 7)) * 8)]);
          oacc[dt] = __builtin_amdgcn_mfma_f32_16x16x32_bf16(aw.v, vf, oacc[dt], 0, 0, 0);
        }
        __builtin_amdgcn_s_setprio(0);
      }
    }

    __syncthreads();
    cur ^= 1;
  }

  // ---- final l reduce (q=r16 lanes) + redistribute + store ----
  float s = lrow;
  s += __shfl_xor(s, 16);
  s += __shfl_xor(s, 32);
  const float linv = 1.0f / s;
  float linvo[4];
#pragma unroll
  for (int r = 0; r < 4; ++r) linvo[r] = __shfl(linv, glsrc + r);
#pragma unroll
  for (int dt = 0; dt < 4; ++dt)
#pragma unroll
    for (int r = 0; r < 4; ++r) {
      const int qrow = qw0 + g * 4 + r;
      Ob[(size_t)qrow * E_ + dt * 16 + r16] = __float2bfloat16(oacc[dt][r] * linvo[r]);
    }
}

extern "C" void kernel_launch(void* const* d_in, const int* in_sizes, int n_in,
                              void* d_out, int out_size, void* d_ws, size_t ws_size,
                              hipStream_t stream) {
  const float* x  = (const float*)d_in[0];
  const float* Wq = (const float*)d_in[1];
  const float* bq = (const float*)d_in[2];
  const float* Wk = (const float*)d_in[3];
  const float* bk = (const float*)d_in[4];
  const float* Wv = (const float*)d_in[5];
  const float* bv = (const float*)d_in[6];
  const float* Wo = (const float*)d_in[7];
  const float* bo = (const float*)d_in[8];
  float* out = (float*)d_out;

  char* ws = (char*)d_ws;
  size_t off = 0;
  auto alloc = [&](size_t bytes) -> char* {
    char* p = ws + off; off += (bytes + 255) & ~(size_t)255; return p;
  };
  bf16* xb    = (bf16*)alloc((size_t)M_ * E_ * 2);
  bf16* Wqkvb = (bf16*)alloc((size_t)3 * E_ * E_ * 2);
  bf16* Wob   = (bf16*)alloc((size_t)E_ * E_ * 2);
  float* bqkv = (float*)alloc((size_t)3 * E_ * 4);
  bf16* Qb    = (bf16*)alloc((size_t)M_ * E_ * 2);   // [b][h][s][d]
  bf16* Kb    = (bf16*)alloc((size_t)M_ * E_ * 2);   // [b][h][s][d]
  bf16* Vtb   = (bf16*)alloc((size_t)M_ * E_ * 2);   // [b][h][d][s]  (V transposed)
  bf16* AOb   = (bf16*)alloc((size_t)M_ * E_ * 2);   // [b][s][e]
  float* sintab = (float*)alloc((size_t)S_ * 32 * 4);
  float* costab = (float*)alloc((size_t)S_ * 32 * 4);

  prep_kernel<<<dim3(8449), 256, 0, stream>>>(x, Wq, Wk, Wv, Wo, bq, bk, bv,
                                              xb, Wqkvb, Wob, bqkv, sintab, costab);

  gemm_qkv<<<dim3(24, 32), 256, 0, stream>>>(xb, Wqkvb, bqkv, Qb, Kb, Vtb, sintab, costab);
  attn_kernel<<<dim3(1024), 256, 0, stream>>>(Qb, Kb, Vtb, AOb);
  gemm_o<<<dim3(512), 256, 0, stream>>>(AOb, Wob, bo, out);
}

// Round 7
// 134.967 us; speedup vs baseline: 1.1776x; 1.1776x over previous
//
#include <hip/hip_runtime.h>
#include <hip/hip_bf16.h>
#include <cstdint>
#include <cstddef>

typedef __hip_bfloat16 bf16;
typedef __attribute__((ext_vector_type(8))) short bf16x8;
typedef __attribute__((ext_vector_type(4))) float f32x4;

#define AS1C(p) ((const __attribute__((address_space(1))) void*)(p))
#define AS3(p)  ((__attribute__((address_space(3))) void*)(p))

constexpr int B_ = 2, S_ = 2048, E_ = 1024, H_ = 16, D_ = 64;
constexpr int M_ = B_ * S_;                      // 4096
constexpr float QSCALE_ = 0.125f * 1.44269504088896340736f;  // 1/sqrt(64) * log2(e)

__device__ __forceinline__ void gload_lds16(const bf16* g, bf16* l) {
  __builtin_amdgcn_global_load_lds(AS1C(g), AS3(l), 16, 0, 0);
}

__device__ __forceinline__ void cast4(const float* __restrict__ in, bf16* __restrict__ out, int i) {
  float4 v = reinterpret_cast<const float4*>(in)[i];
  union { bf16 b[4]; short4 s; } u;
  u.b[0] = __float2bfloat16(v.x);
  u.b[1] = __float2bfloat16(v.y);
  u.b[2] = __float2bfloat16(v.z);
  u.b[3] = __float2bfloat16(v.w);
  reinterpret_cast<short4*>(out)[i] = u.s;
}

// ---------------- fused prep: casts + rope tables + bias concat ----------------
__global__ void prep_kernel(const float* __restrict__ x,
                            const float* __restrict__ Wq, const float* __restrict__ Wk,
                            const float* __restrict__ Wv, const float* __restrict__ Wo,
                            const float* __restrict__ bq, const float* __restrict__ bk,
                            const float* __restrict__ bv,
                            bf16* __restrict__ xb, bf16* __restrict__ Wqkvb,
                            bf16* __restrict__ Wob, float* __restrict__ bqkv,
                            float* __restrict__ sintab, float* __restrict__ costab) {
  const int b = blockIdx.x, t = threadIdx.x;
  if (b < 4096) {
    cast4(x, xb, b * 256 + t);
  } else if (b < 5120) {
    cast4(Wo, Wob, (b - 4096) * 256 + t);
  } else if (b < 8192) {
    const int i = (b - 5120) * 256 + t;
    const int which = i >> 18;
    const int j = i & ((1 << 18) - 1);
    const float* src = which == 0 ? Wq : (which == 1 ? Wk : Wv);
    cast4(src, Wqkvb + (size_t)which * E_ * E_, j);
  } else if (b < 8448) {
    const int idx = (b - 8192) * 256 + t;
    const int s = idx >> 5, i = idx & 31;
    float inv = powf(10000.0f, -(float)i / 32.0f);
    float ang = (float)s * inv;
    sintab[idx] = sinf(ang);
    costab[idx] = cosf(ang);
  } else {
    for (int j = t; j < 768; j += 256) {
      const int which = j >> 8, jj = j & 255;
      const float* src = which == 0 ? bq : (which == 1 ? bk : bv);
      reinterpret_cast<float4*>(bqkv)[j] = reinterpret_cast<const float4*>(src)[jj];
    }
  }
}

// ---------------- QKV GEMM: C = x * Wqkv^T + bias; rope q/k; V stored TRANSPOSED ----------------
// Q,K scatter to [b][h][s][d]; V-blocks (n0>=2048) transpose via LDS and write [b][h][d][s]
// with coalesced bf16x8 stores.
__global__ __launch_bounds__(256)
void gemm_qkv(const bf16* __restrict__ A, const bf16* __restrict__ W,
              const float* __restrict__ bias,
              bf16* __restrict__ Qo, bf16* __restrict__ Ko, bf16* __restrict__ Vo,
              const float* __restrict__ sintab, const float* __restrict__ costab)
{
  constexpr int K = 1024, BK = 32;
  __shared__ __align__(16) bf16 smem[128 * 136];   // 34.8 KB; As|Bs alias + V-transpose buffer
  bf16* As = smem;                                  // 128*32
  bf16* Bs = smem + 128 * 32;                       // 128*32
  const int tid = threadIdx.x;
  const int lane = tid & 63, wid = tid >> 6;
  const int g = lane >> 4, r16 = lane & 15;
  const int wr = wid >> 1, wc = wid & 1;

  const int nwg = gridDim.x * gridDim.y;
  const int flat = blockIdx.y * gridDim.x + blockIdx.x;
  const int cpx = nwg >> 3;
  const int f2 = (flat & 7) * cpx + (flat >> 3);
  const int m0 = (f2 / gridDim.x) * 128, n0 = (f2 % gridDim.x) * 128;

  const f32x4 fz = {0.f, 0.f, 0.f, 0.f};
  f32x4 acc[4][4];
#pragma unroll
  for (int mi = 0; mi < 4; ++mi)
#pragma unroll
    for (int ni = 0; ni < 4; ++ni) acc[mi][ni] = fz;

  const bf16* Abase = A + (size_t)m0 * K;
  const bf16* Wbase = W + (size_t)n0 * K;
  const int c0 = tid, c1 = 256 + tid;

  for (int k0 = 0; k0 < K; k0 += BK) {
    __syncthreads();
    gload_lds16(Abase + (size_t)(c0 >> 2) * K + k0 + (c0 & 3) * 8, As + c0 * 8);
    gload_lds16(Abase + (size_t)(c1 >> 2) * K + k0 + (c1 & 3) * 8, As + c1 * 8);
    gload_lds16(Wbase + (size_t)(c0 >> 2) * K + k0 + (c0 & 3) * 8, Bs + c0 * 8);
    gload_lds16(Wbase + (size_t)(c1 >> 2) * K + k0 + (c1 & 3) * 8, Bs + c1 * 8);
    __syncthreads();

    bf16x8 af[4], bfr[4];
#pragma unroll
    for (int mi = 0; mi < 4; ++mi)
      af[mi] = *reinterpret_cast<const bf16x8*>(As + (wr * 64 + mi * 16 + r16) * BK + 8 * g);
#pragma unroll
    for (int ni = 0; ni < 4; ++ni)
      bfr[ni] = *reinterpret_cast<const bf16x8*>(Bs + (wc * 64 + ni * 16 + r16) * BK + 8 * g);
    __builtin_amdgcn_s_setprio(1);
#pragma unroll
    for (int mi = 0; mi < 4; ++mi)
#pragma unroll
      for (int ni = 0; ni < 4; ++ni)
        acc[mi][ni] = __builtin_amdgcn_mfma_f32_16x16x32_bf16(af[mi], bfr[ni], acc[mi][ni], 0, 0, 0);
    __builtin_amdgcn_s_setprio(0);
  }

  const int b = m0 >> 11;
  if (n0 >= 2048) {
    // ---- V block: transpose 128x128 tile via LDS, coalesced V^T writes ----
    __syncthreads();                                // K-loop LDS reads complete
#pragma unroll
    for (int mi = 0; mi < 4; ++mi) {
#pragma unroll
      for (int ni = 0; ni < 4; ++ni) {
        const int n_local = wc * 64 + ni * 16 + r16;
        const float bv = bias[n0 + n_local];
        const int m_base = wr * 64 + mi * 16 + g * 4;
        union { bf16 b4[4]; short4 s4; } u;
#pragma unroll
        for (int r = 0; r < 4; ++r) u.b4[r] = __float2bfloat16(acc[mi][ni][r] + bv);
        *reinterpret_cast<short4*>(&smem[n_local * 136 + m_base]) = u.s4;
      }
    }
    __syncthreads();
    const int srow0 = m0 & (S_ - 1);
#pragma unroll
    for (int i = 0; i < 8; ++i) {
      const int c = i * 256 + tid;
      const int row = c >> 4, cc = c & 15;
      const bf16x8 v = *reinterpret_cast<const bf16x8*>(&smem[row * 136 + cc * 8]);
      const int n = n0 + row;
      const int h = (n >> 6) & 15, d = n & 63;
      *reinterpret_cast<bf16x8*>(&Vo[((size_t)(b * H_ + h) * D_ + d) * S_ + srow0 + cc * 8]) = v;
    }
  } else {
    // ---- Q/K block: rope + scatter to [b][h][s][d] ----
#pragma unroll
    for (int mi = 0; mi < 4; ++mi) {
#pragma unroll
      for (int ni = 0; ni < 4; ++ni) {
        const int gn = n0 + wc * 64 + ni * 16 + r16;
        const float bv = bias[gn];
#pragma unroll
        for (int r = 0; r < 4; ++r) {
          const int gm = m0 + wr * 64 + mi * 16 + g * 4 + r;
          float val = acc[mi][ni][r] + bv;
          const int d = gn & 63;
          const int srow = gm & (S_ - 1);
          const float cs = costab[srow * 32 + (d >> 1)];
          const float sn = sintab[srow * 32 + (d >> 1)];
          const float pv = __shfl_xor(val, 1);
          val = (d & 1) ? (val * cs + pv * sn) : (val * cs - pv * sn);
          const int h = (gn >> 6) & 15;
          const size_t bh = (size_t)(b * H_ + h);
          if (gn < 1024) {
            Qo[(bh * S_ + srow) * D_ + d] = __float2bfloat16(val * QSCALE_);
          } else {
            Ko[(bh * S_ + srow) * D_ + d] = __float2bfloat16(val);
          }
        }
      }
    }
  }
}

// ---------------- O-projection GEMM: BM=64 x BN=128 (512 blocks) ----------------
__global__ __launch_bounds__(256)
void gemm_o(const bf16* __restrict__ A, const bf16* __restrict__ W,
            const float* __restrict__ bias, float* __restrict__ outF)
{
  constexpr int K = 1024, BK = 32;
  __shared__ __align__(16) bf16 As[64 * BK];
  __shared__ __align__(16) bf16 Bs[128 * BK];
  const int tid = threadIdx.x;
  const int lane = tid & 63;
  const int wc = tid >> 6;
  const int g = lane >> 4, r16 = lane & 15;

  const int flat = blockIdx.x;                    // 512
  const int f2 = (flat & 7) * 64 + (flat >> 3);
  const int m0 = (f2 >> 3) * 64, n0 = (f2 & 7) * 128;

  const f32x4 fz = {0.f, 0.f, 0.f, 0.f};
  f32x4 acc[4][2];
#pragma unroll
  for (int mi = 0; mi < 4; ++mi)
#pragma unroll
    for (int ni = 0; ni < 2; ++ni) acc[mi][ni] = fz;

  const bf16* Abase = A + (size_t)m0 * K;
  const bf16* Wbase = W + (size_t)n0 * K;
  const int c0 = tid, c1 = 256 + tid;

  for (int k0 = 0; k0 < K; k0 += BK) {
    __syncthreads();
    gload_lds16(Abase + (size_t)(c0 >> 2) * K + k0 + (c0 & 3) * 8, As + c0 * 8);
    gload_lds16(Wbase + (size_t)(c0 >> 2) * K + k0 + (c0 & 3) * 8, Bs + c0 * 8);
    gload_lds16(Wbase + (size_t)(c1 >> 2) * K + k0 + (c1 & 3) * 8, Bs + c1 * 8);
    __syncthreads();

    bf16x8 af[4], bfr[2];
#pragma unroll
    for (int mi = 0; mi < 4; ++mi)
      af[mi] = *reinterpret_cast<const bf16x8*>(As + (mi * 16 + r16) * BK + 8 * g);
#pragma unroll
    for (int ni = 0; ni < 2; ++ni)
      bfr[ni] = *reinterpret_cast<const bf16x8*>(Bs + (wc * 32 + ni * 16 + r16) * BK + 8 * g);
    __builtin_amdgcn_s_setprio(1);
#pragma unroll
    for (int mi = 0; mi < 4; ++mi)
#pragma unroll
      for (int ni = 0; ni < 2; ++ni)
        acc[mi][ni] = __builtin_amdgcn_mfma_f32_16x16x32_bf16(af[mi], bfr[ni], acc[mi][ni], 0, 0, 0);
    __builtin_amdgcn_s_setprio(0);
  }

#pragma unroll
  for (int mi = 0; mi < 4; ++mi)
#pragma unroll
    for (int ni = 0; ni < 2; ++ni) {
      const int gn = n0 + wc * 32 + ni * 16 + r16;
      const float bv = bias[gn];
#pragma unroll
      for (int r = 0; r < 4; ++r) {
        const int gm = m0 + mi * 16 + g * 4 + r;
        outF[(size_t)gm * 1024 + gn] = acc[mi][ni][r] + bv;
      }
    }
}

// ---------------- causal flash attention v6 ----------------
// Swapped QK^T (lane owns q = qw0+r16, 16 k's), in-register P repack via cvt_pk + shfl,
// V^T staged from global [bh][d][s] via gload_lds. 1024 blocks heavy-first, 4 blocks/CU.
__global__ __launch_bounds__(256, 4)
void attn_kernel(const bf16* __restrict__ Q, const bf16* __restrict__ Kg,
                 const bf16* __restrict__ Vtg, bf16* __restrict__ Og)
{
  __shared__ __align__(16) bf16 Ks[2][64 * 64];   // [k][d], chunk-xor-swizzled source
  __shared__ __align__(16) bf16 Vs[2][64 * 64];   // [d][k], chunk-xor-swizzled source
  const int flat = blockIdx.x;
  const int bh = flat & 31;
  const int qblk = 31 - (flat >> 5);              // heavy-first
  const int tid = threadIdx.x, lane = tid & 63, wid = tid >> 6;
  const int g = lane >> 4, r16 = lane & 15;
  const bf16* Qb = Q + (size_t)bh * S_ * D_;
  const bf16* Kb = Kg + (size_t)bh * S_ * D_;
  const bf16* Vb = Vtg + (size_t)bh * D_ * S_;
  const int b = bh >> 4, h = bh & 15;
  bf16* Ob = Og + (size_t)b * S_ * E_ + h * D_;

  const int q0 = qblk * 64;
  const int qw0 = q0 + wid * 16;
  const int nkt = qblk + 1;
  const f32x4 fz = {0.f, 0.f, 0.f, 0.f};

  bf16x8 qf[2];
#pragma unroll
  for (int hh = 0; hh < 2; ++hh)
    qf[hh] = *reinterpret_cast<const bf16x8*>(Qb + (size_t)(qw0 + r16) * 64 + hh * 32 + 8 * g);

  f32x4 oacc[4];
#pragma unroll
  for (int dt = 0; dt < 4; ++dt) oacc[dt] = fz;
  float mrow = -__builtin_inff();
  float lrow = 0.f;

  const int kc0 = tid, kc1 = 256 + tid;
  const int glsrc = (g << 4) + (g << 2);          // 20*g

  auto stage = [&](const bf16* srcbase, size_t rowstride, bf16* dst) {
    const int r0 = kc0 >> 3, cc0 = kc0 & 7;
    gload_lds16(srcbase + (size_t)r0 * rowstride + ((cc0 ^ (r0 & 7)) * 8), dst + kc0 * 8);
    const int r1 = kc1 >> 3, cc1 = kc1 & 7;
    gload_lds16(srcbase + (size_t)r1 * rowstride + ((cc1 ^ (r1 & 7)) * 8), dst + kc1 * 8);
  };

  stage(Kb, 64, Ks[0]);
  stage(Vb, S_, Vs[0]);
  __syncthreads();
  int cur = 0;

  for (int kt = 0; kt < nkt; ++kt) {
    const int k0 = kt * 64;
    if (kt + 1 < nkt) {
      stage(Kb + (size_t)(k0 + 64) * 64, 64, Ks[cur ^ 1]);
      stage(Vb + (k0 + 64), S_, Vs[cur ^ 1]);
    }

    if (k0 <= qw0 + 15) {
      const bf16* ksp = Ks[cur];
      const bf16* vsp = Vs[cur];
      const int sw = r16 & 7;
      f32x4 ps[4];
      __builtin_amdgcn_s_setprio(1);
#pragma unroll
      for (int kf = 0; kf < 4; ++kf) {
        const int krow = kf * 16 + r16;
        const bf16x8 ka = *reinterpret_cast<const bf16x8*>(&ksp[krow * 64 + ((g ^ sw) * 8)]);
        const bf16x8 kb = *reinterpret_cast<const bf16x8*>(&ksp[krow * 64 + (((g + 4) ^ sw) * 8)]);
        f32x4 sa = __builtin_amdgcn_mfma_f32_16x16x32_bf16(ka, qf[0], fz, 0, 0, 0);
        ps[kf] = __builtin_amdgcn_mfma_f32_16x16x32_bf16(kb, qf[1], sa, 0, 0, 0);
      }
      __builtin_amdgcn_s_setprio(0);
      if (k0 + 63 > qw0) {
        const int qmk = qw0 + r16 - k0;
#pragma unroll
        for (int kf = 0; kf < 4; ++kf)
#pragma unroll
          for (int r = 0; r < 4; ++r)
            if (kf * 16 + 4 * g + r > qmk) ps[kf][r] = -1e30f;
      }
      float tm = fmaxf(fmaxf(ps[0][0], ps[0][1]), fmaxf(ps[0][2], ps[0][3]));
#pragma unroll
      for (int kf = 1; kf < 4; ++kf)
        tm = fmaxf(tm, fmaxf(fmaxf(ps[kf][0], ps[kf][1]), fmaxf(ps[kf][2], ps[kf][3])));
      tm = fmaxf(tm, __shfl_xor(tm, 16));
      tm = fmaxf(tm, __shfl_xor(tm, 32));
      if (__any((tm - mrow > 8.f) ? 1 : 0)) {
        const float mn = fmaxf(mrow, tm);
        const float scl = exp2f(mrow - mn);
        mrow = mn;
        lrow *= scl;
        float sclo[4];
#pragma unroll
        for (int r = 0; r < 4; ++r) sclo[r] = __shfl(scl, glsrc + r);
#pragma unroll
        for (int dt = 0; dt < 4; ++dt)
#pragma unroll
          for (int r = 0; r < 4; ++r) oacc[dt][r] *= sclo[r];
      }
      float ssum = 0.f;
#pragma unroll
      for (int kf = 0; kf < 4; ++kf)
#pragma unroll
        for (int r = 0; r < 4; ++r) {
          const float p = exp2f(ps[kf][r] - mrow);
          ps[kf][r] = p;
          ssum += p;
        }
      lrow += ssum;
      unsigned int pk[4][2];
#pragma unroll
      for (int kf = 0; kf < 4; ++kf)
#pragma unroll
        for (int w = 0; w < 2; ++w) {
          unsigned int rr;
          asm("v_cvt_pk_bf16_f32 %0, %1, %2" : "=v"(rr) : "v"(ps[kf][2 * w]), "v"(ps[kf][2 * w + 1]));
          pk[kf][w] = rr;
        }
      const int srcA = ((g & 1) << 5) + r16;
      const bool ghi = g >= 2;
#pragma unroll
      for (int ks = 0; ks < 2; ++ks) {
        const unsigned int a0 = (unsigned)__shfl((int)pk[2 * ks][0], srcA);
        const unsigned int b0 = (unsigned)__shfl((int)pk[2 * ks + 1][0], srcA);
        const unsigned int a1 = (unsigned)__shfl((int)pk[2 * ks][1], srcA);
        const unsigned int b1 = (unsigned)__shfl((int)pk[2 * ks + 1][1], srcA);
        const unsigned int a2 = (unsigned)__shfl((int)pk[2 * ks][0], srcA + 16);
        const unsigned int b2 = (unsigned)__shfl((int)pk[2 * ks + 1][0], srcA + 16);
        const unsigned int a3 = (unsigned)__shfl((int)pk[2 * ks][1], srcA + 16);
        const unsigned int b3 = (unsigned)__shfl((int)pk[2 * ks + 1][1], srcA + 16);
        union { unsigned int w[4]; bf16x8 v; } aw;
        aw.w[0] = ghi ? b0 : a0;
        aw.w[1] = ghi ? b1 : a1;
        aw.w[2] = ghi ? b2 : a2;
        aw.w[3] = ghi ? b3 : a3;
        __builtin_amdgcn_s_setprio(1);
#pragma unroll
        for (int dt = 0; dt < 4; ++dt) {
          const int d = dt * 16 + r16;
          const bf16x8 vf = *reinterpret_cast<const bf16x8*>(
              &vsp[d * 64 + (((ks * 4 + g) ^ (r16 & 7)) * 8)]);
          oacc[dt] = __builtin_amdgcn_mfma_f32_16x16x32_bf16(aw.v, vf, oacc[dt], 0, 0, 0);
        }
        __builtin_amdgcn_s_setprio(0);
      }
    }

    __syncthreads();
    cur ^= 1;
  }

  float s = lrow;
  s += __shfl_xor(s, 16);
  s += __shfl_xor(s, 32);
  const float linv = 1.0f / s;
  float linvo[4];
#pragma unroll
  for (int r = 0; r < 4; ++r) linvo[r] = __shfl(linv, glsrc + r);
#pragma unroll
  for (int dt = 0; dt < 4; ++dt)
#pragma unroll
    for (int r = 0; r < 4; ++r) {
      const int qrow = qw0 + g * 4 + r;
      Ob[(size_t)qrow * E_ + dt * 16 + r16] = __float2bfloat16(oacc[dt][r] * linvo[r]);
    }
}

extern "C" void kernel_launch(void* const* d_in, const int* in_sizes, int n_in,
                              void* d_out, int out_size, void* d_ws, size_t ws_size,
                              hipStream_t stream) {
  const float* x  = (const float*)d_in[0];
  const float* Wq = (const float*)d_in[1];
  const float* bq = (const float*)d_in[2];
  const float* Wk = (const float*)d_in[3];
  const float* bk = (const float*)d_in[4];
  const float* Wv = (const float*)d_in[5];
  const float* bv = (const float*)d_in[6];
  const float* Wo = (const float*)d_in[7];
  const float* bo = (const float*)d_in[8];
  float* out = (float*)d_out;

  char* ws = (char*)d_ws;
  size_t off = 0;
  auto alloc = [&](size_t bytes) -> char* {
    char* p = ws + off; off += (bytes + 255) & ~(size_t)255; return p;
  };
  bf16* xb    = (bf16*)alloc((size_t)M_ * E_ * 2);
  bf16* Wqkvb = (bf16*)alloc((size_t)3 * E_ * E_ * 2);
  bf16* Wob   = (bf16*)alloc((size_t)E_ * E_ * 2);
  float* bqkv = (float*)alloc((size_t)3 * E_ * 4);
  bf16* Qb    = (bf16*)alloc((size_t)M_ * E_ * 2);   // [b][h][s][d]
  bf16* Kb    = (bf16*)alloc((size_t)M_ * E_ * 2);   // [b][h][s][d]
  bf16* Vtb   = (bf16*)alloc((size_t)M_ * E_ * 2);   // [b][h][d][s]  (V transposed)
  bf16* AOb   = (bf16*)alloc((size_t)M_ * E_ * 2);   // [b][s][e]
  float* sintab = (float*)alloc((size_t)S_ * 32 * 4);
  float* costab = (float*)alloc((size_t)S_ * 32 * 4);

  prep_kernel<<<dim3(8449), 256, 0, stream>>>(x, Wq, Wk, Wv, Wo, bq, bk, bv,
                                              xb, Wqkvb, Wob, bqkv, sintab, costab);

  gemm_qkv<<<dim3(24, 32), 256, 0, stream>>>(xb, Wqkvb, bqkv, Qb, Kb, Vtb, sintab, costab);
  attn_kernel<<<dim3(1024), 256, 0, stream>>>(Qb, Kb, Vtb, AOb);
  gemm_o<<<dim3(512), 256, 0, stream>>>(AOb, Wob, bo, out);
}